// Round 12
// baseline (27.777 us; speedup 1.0000x reference)
//
#include <hip/hip_runtime.h>
#include <math.h>

// Problem constants (match reference)
#define Bq 4
#define Nq 80
#define CHq 64
#define GAMMAq 4.0f
#define EPSq 1e-6f
#define PCWL 100     // LDS row pad
#define NQUAD 24     // float4 quads per (na,u): 96 floats

// Packed comp map (per (na,u), 96 floats, stored as quads interleaved by u):
//   0-2   A00[k]        3-5   A10[k]       6-14  C01[k][j]
//   15-23 P0[k][j]      24-32 P1[k][j]     33-41 P2[k][j]
//   42 r1s  43-45 r1v   46-47 pad
//   48+c (c=0..41): wr2-mixed copies of comps 0..41 (r2 fold)   90-95 pad
// Global layout: pc_quad[ na ][ c4 0..23 ][ u 0..15 ]  (float4 each)
//
// XCD swizzle (both kernels, bijective over 320 tasks):
//   L = blockIdx & 7, idx = blockIdx >> 3; n = L >> 1, node = (L&1)*40 + idx
// -> pc[n][a-half] produced AND consumed on the same XCD (L2-local, perf-only).

// ---------------------------------------------------------------------------
// Kernel 1: 320 blocks x 256 threads, one (n,a) per block.
//  stage 0: LDS staging of inputs + all weights (coalesced; padded rows)
//  stage 1 (128 thr = 16u x {3k + r1} x 2 v-halves): 8-v contractions from LDS
//  stage 2 (96 thr, merged): half-combine + r2 fold in one pass
//  stage 3 (256 thr): interleaved quad write-out
// ---------------------------------------------------------------------------
__global__ __launch_bounds__(256) void se3_precomp(
    const float* __restrict__ h_nei,   // [B][CH][N]
    const float* __restrict__ x,       // [B][CH][N]
    const float* __restrict__ w00,     // [M][M][3]
    const float* __restrict__ w10,
    const float* __restrict__ w01,
    const float* __restrict__ w11,     // [3][M][M][3]
    const float* __restrict__ wr10,    // [M][M]
    const float* __restrict__ wr11,
    const float* __restrict__ wr20,    // [M][M]
    const float* __restrict__ wr21,
    float* __restrict__ pc)
{
    const int L   = blockIdx.x & 7;
    const int idx = blockIdx.x >> 3;           // 0..39
    const int n   = L >> 1;
    const int a   = (L & 1) * 40 + idx;
    const int na  = n * Nq + a;
    const int tid = threadIdx.x;               // 0..255

    __shared__ float hsh[64];
    __shared__ float xsh[64];
    __shared__ float w00s[784], w10s[784], w01s[784];   // [u][v*3+k], 48->49 pad
    __shared__ float w11s[3][784];
    __shared__ float wr10s[272], wr11s[272];            // [u][v], 16->17 pad
    __shared__ float psh[2][42][16];
    __shared__ float r1sh[2][4][16];
    __shared__ float pout[16][PCWL];

    if (tid < 64)       hsh[tid]      = h_nei[(size_t)n * CHq * Nq + tid * Nq + a];
    else if (tid < 128) xsh[tid - 64] = x    [(size_t)n * CHq * Nq + (tid - 64) * Nq + a];

    // stage 0: weights -> LDS (coalesced global reads; padded LDS rows)
    for (int e = tid; e < 768; e += 256) {
        const int u = e / 48, r = e - u * 48;
        const int d = u * 49 + r;
        w00s[d]    = w00[e];
        w10s[d]    = w10[e];
        w01s[d]    = w01[e];
        w11s[0][d] = w11[e];
        w11s[1][d] = w11[768 + e];
        w11s[2][d] = w11[1536 + e];
    }
    if (tid < 256) {
        const int u = tid >> 4, v = tid & 15;
        wr10s[u * 17 + v] = wr10[tid];
        wr11s[u * 17 + v] = wr11[tid];
    }
    __syncthreads();

    // ---- stage 1: 128 threads = (u, q) with q = (kk 0..3, half) ----
    if (tid < 128) {
        const int u    = tid & 15;
        const int q    = tid >> 4;     // 0..7
        const int half = q & 1;
        const int kk   = q >> 1;       // 0..3
        const int v0   = half * 8;

        if (kk < 3) {
            const int k = kk;
            float a00 = 0.f, a10 = 0.f;
            float c[3] = {0.f,0.f,0.f}, p0[3] = {0.f,0.f,0.f};
            float p1[3] = {0.f,0.f,0.f}, p2[3] = {0.f,0.f,0.f};
#pragma unroll
            for (int i = 0; i < 8; ++i) {
                const int v  = v0 + i;
                const int wi = u * 49 + v * 3 + k;
                const float s = hsh[v];
                a00 += w00s[wi] * s;
                a10 += w10s[wi] * s;
                const float w01v = w01s[wi];
                const float w110 = w11s[0][wi];
                const float w111 = w11s[1][wi];
                const float w112 = w11s[2][wi];
#pragma unroll
                for (int j = 0; j < 3; ++j) {
                    const float Vj = hsh[16 + v * 3 + j];
                    c[j]  += w01v * Vj;
                    p0[j] += w110 * Vj;
                    p1[j] += w111 * Vj;
                    p2[j] += w112 * Vj;
                }
            }
            psh[half][0 + k][u] = a00;
            psh[half][3 + k][u] = a10;
#pragma unroll
            for (int j = 0; j < 3; ++j) {
                psh[half][6  + k * 3 + j][u] = c[j];
                psh[half][15 + k * 3 + j][u] = p0[j];
                psh[half][24 + k * 3 + j][u] = p1[j];
                psh[half][33 + k * 3 + j][u] = p2[j];
            }
        } else {
            // r1 = SI(x) partial for this v-half
            float r1s = 0.f, r1v[3] = {0.f, 0.f, 0.f};
#pragma unroll
            for (int i = 0; i < 8; ++i) {
                const int v = v0 + i;
                r1s += wr10s[u * 17 + v] * xsh[v];
                const float wv = wr11s[u * 17 + v];
#pragma unroll
                for (int j = 0; j < 3; ++j) r1v[j] += wv * xsh[16 + v * 3 + j];
            }
            r1sh[half][0][u] = r1s;
#pragma unroll
            for (int j = 0; j < 3; ++j) r1sh[half][1 + j][u] = r1v[j];
        }
    }
    __syncthreads();

    // ---- stage 2 (merged): half-combine + r2 fold in one pass (96 thr) ----
    if (tid < 96) {
        const int u  = tid & 15;
        const int kk = tid >> 4;       // 0..5
#pragma unroll
        for (int c = kk * 7; c < kk * 7 + 7; ++c) {
            pout[u][c] = psh[0][c][u] + psh[1][c][u];
            const bool scalarType = (c < 3) || (c >= 6 && c < 15);
            const float* W = scalarType ? wr20 : wr21;
            float acc = 0.f;
#pragma unroll
            for (int v = 0; v < 16; ++v)
                acc += W[u * 16 + v] * (psh[0][c][v] + psh[1][c][v]);
            pout[u][48 + c] = acc;
        }
        if (kk == 0) {
#pragma unroll
            for (int j = 0; j < 4; ++j)
                pout[u][42 + j] = r1sh[0][j][u] + r1sh[1][j][u];
            pout[u][46] = 0.f; pout[u][47] = 0.f;
#pragma unroll
            for (int j = 90; j < 96; ++j) pout[u][j] = 0.f;
        }
    }
    __syncthreads();

    // ---- stage 3: interleaved quad write (384 quad-tasks on 256 threads) ----
    {
        float4* dst = reinterpret_cast<float4*>(pc) + (size_t)na * (NQUAD * 16);
#pragma unroll
        for (int i = 0; i < 2; ++i) {
            const int qi = tid + i * 256;      // 0..511
            if (qi < 384) {
                const int c4 = qi >> 4;
                const int u  = qi & 15;
                dst[c4 * 16 + u] = make_float4(pout[u][c4 * 4 + 0], pout[u][c4 * 4 + 1],
                                               pout[u][c4 * 4 + 2], pout[u][c4 * 4 + 3]);
            }
        }
    }
}

// ---------------------------------------------------------------------------
// Kernel 2: 320 blocks x 256 threads (16 a-groups x 16 u), XCD-swizzled.
// Software-pipelined barrier-free a-loop (prefetch i+1 while computing i);
// 128-thread parallel epilogue dots; 16-thread transcendental tail.
// ---------------------------------------------------------------------------
__global__ __launch_bounds__(256, 1) void se3_main(
    const float* __restrict__ x,       // [B][CH][N]
    const float* __restrict__ hdiff,   // [B][N][N][3]
    const float* __restrict__ mask,    // [B][N][N]
    const float* __restrict__ wz0,     // [M][2M]
    const float* __restrict__ wz1,
    const float* __restrict__ wp0,
    const float* __restrict__ wp1,
    const float* __restrict__ pc,
    float* __restrict__ out)           // [B][CH][N]
{
    const int L     = blockIdx.x & 7;
    const int idx   = blockIdx.x >> 3;         // 0..39
    const int n     = L >> 1;
    const int bnode = (L & 1) * 40 + idx;
    const int tid   = threadIdx.x;
    const int g     = tid >> 4;        // a-group 0..15
    const int u     = tid & 15;        // channel 0..15

    __shared__ float wsh[4][512];      // wz0, wz1, wp0, wp1
    __shared__ float redW[4][8][16];
    __shared__ float sumHs[64], sumGs[64];
    __shared__ float epish[8][16];

    const float4* pcbase = reinterpret_cast<const float4*>(pc)
                         + (size_t)(n * Nq) * (NQUAD * 16) + u;

    float pa[2][48], pb[2][44];   // [it&1] static after full unroll -> registers

    // prologue: issue iteration-0 pc loads FIRST (longest latency)
    {
        const float4* p4 = pcbase + (size_t)g * (NQUAD * 16);
#pragma unroll
        for (int i = 0; i < 12; ++i)
            *reinterpret_cast<float4*>(&pa[0][i * 4]) = p4[i * 16];
#pragma unroll
        for (int i = 0; i < 11; ++i)
            *reinterpret_cast<float4*>(&pb[0][i * 4]) = p4[(12 + i) * 16];
    }

#pragma unroll
    for (int i = 0; i < 2; ++i) {
        const int widx = tid + i * 256;
        wsh[0][widx] = wz0[widx];
        wsh[1][widx] = wz1[widx];
        wsh[2][widx] = wp0[widx];
        wsh[3][widx] = wp1[widx];
    }

    const float* drow = hdiff + (size_t)(n * Nq + bnode) * Nq * 3;
    const float* mrow = mask  + (size_t)(n * Nq + bnode) * Nq;
    const float third = 1.0f / 3.0f;

    // hoist all geometry (static indices after unroll)
    float dg[5][3], mg[5];
#pragma unroll
    for (int it = 0; it < 5; ++it) {
        const int a = it * 16 + g;
        dg[it][0] = drow[a * 3 + 0];
        dg[it][1] = drow[a * 3 + 1];
        dg[it][2] = drow[a * 3 + 2];
        mg[it]    = mrow[a];
    }

    float shs = 0.f, shv0 = 0.f, shv1 = 0.f, shv2 = 0.f;
    float sgs = 0.f, sgv0 = 0.f, sgv1 = 0.f, sgv2 = 0.f;

#pragma unroll
    for (int it = 0; it < 5; ++it) {
        const int cur = it & 1, nxt = cur ^ 1;

        if (it < 4) {   // issue next iteration's loads; latency hides under compute
            const int a2 = (it + 1) * 16 + g;
            const float4* p4 = pcbase + (size_t)a2 * (NQUAD * 16);
#pragma unroll
            for (int i = 0; i < 12; ++i)
                *reinterpret_cast<float4*>(&pa[nxt][i * 4]) = p4[i * 16];
#pragma unroll
            for (int i = 0; i < 11; ++i)
                *reinterpret_cast<float4*>(&pb[nxt][i * 4]) = p4[(12 + i) * 16];
        }

        const float d0 = dg[it][0], d1 = dg[it][1], d2 = dg[it][2];
        const float m  = mg[it];

        const float rad = sqrtf(d0 * d0 + d1 * d1 + d2 * d2 + EPSq);
        const float inv = 1.0f / rad;
        const float nh0 = d0 * inv, nh1 = d1 * inv, nh2 = d2 * inv;
        float rb[3];
        rb[0] = __expf(-GAMMAq * rad * rad);
        { float t1 = rad - 0.5f; rb[1] = __expf(-GAMMAq * t1 * t1); }
        { float t2 = rad - 1.0f; rb[2] = __expf(-GAMMAq * t2 * t2); }

        float as_ = 0.f, a10 = 0.f;
        float c01[3] = {0.f,0.f,0.f}, p0[3] = {0.f,0.f,0.f};
        float p1[3] = {0.f,0.f,0.f}, p2[3] = {0.f,0.f,0.f};
        float bs_ = 0.f, b10 = 0.f;
        float bc01[3] = {0.f,0.f,0.f}, bp0[3] = {0.f,0.f,0.f};
        float bp1[3] = {0.f,0.f,0.f}, bp2[3] = {0.f,0.f,0.f};
#pragma unroll
        for (int k = 0; k < 3; ++k) {
            const float r = rb[k];
            as_ += r * pa[cur][0 + k];
            a10 += r * pa[cur][3 + k];
            bs_ += r * pb[cur][0 + k];
            b10 += r * pb[cur][3 + k];
#pragma unroll
            for (int j = 0; j < 3; ++j) {
                c01[j]  += r * pa[cur][6  + k * 3 + j];
                p0[j]   += r * pa[cur][15 + k * 3 + j];
                p1[j]   += r * pa[cur][24 + k * 3 + j];
                p2[j]   += r * pa[cur][33 + k * 3 + j];
                bc01[j] += r * pb[cur][6  + k * 3 + j];
                bp0[j]  += r * pb[cur][15 + k * 3 + j];
                bp1[j]  += r * pb[cur][24 + k * 3 + j];
                bp2[j]  += r * pb[cur][33 + k * 3 + j];
            }
        }

        const float hcs = m * (as_ + c01[0] * nh0 + c01[1] * nh1 + c01[2] * nh2);
        const float cr0 = p1[1] * nh2 - p1[2] * nh1;
        const float cr1 = p1[2] * nh0 - p1[0] * nh2;
        const float cr2 = p1[0] * nh1 - p1[1] * nh0;
        const float pd  = p2[0] * nh0 + p2[1] * nh1 + p2[2] * nh2;
        const float hv0 = m * (nh0 * a10 + p0[0] + cr0 + nh0 * pd - p2[0] * third);
        const float hv1 = m * (nh1 * a10 + p0[1] + cr1 + nh1 * pd - p2[1] * third);
        const float hv2 = m * (nh2 * a10 + p0[2] + cr2 + nh2 * pd - p2[2] * third);

        const float r2s = m * (bs_ + bc01[0] * nh0 + bc01[1] * nh1 + bc01[2] * nh2);
        const float br0 = bp1[1] * nh2 - bp1[2] * nh1;
        const float br1 = bp1[2] * nh0 - bp1[0] * nh2;
        const float br2 = bp1[0] * nh1 - bp1[1] * nh0;
        const float bpd = bp2[0] * nh0 + bp2[1] * nh1 + bp2[2] * nh2;
        const float r2v0 = m * (nh0 * b10 + bp0[0] + br0 + nh0 * bpd - bp2[0] * third);
        const float r2v1 = m * (nh1 * b10 + bp0[1] + br1 + nh1 * bpd - bp2[1] * third);
        const float r2v2 = m * (nh2 * b10 + bp0[2] + br2 + nh2 * bpd - bp2[2] * third);

        const float r1s  = pa[cur][42];
        const float r1v0 = pa[cur][43], r1v1 = pa[cur][44], r1v2 = pa[cur][45];

        const float rs  = 1.0f / (1.0f + __expf(-(r1s + r2s)));
        const float wv0 = r1v0 + r2v0, wv1 = r1v1 + r2v1, wv2 = r1v2 + r2v2;
        const float nn  = sqrtf(wv0 * wv0 + wv1 * wv1 + wv2 * wv2 + EPSq);
        const float sc  = (1.0f / (1.0f + __expf(-nn))) / nn;
        const float rv0 = wv0 * sc, rv1 = wv1 * sc, rv2 = wv2 * sc;
        const float fs  = fabsf(rs);
        const float fv  = sqrtf(rv0 * rv0 + rv1 * rv1 + rv2 * rv2 + EPSq);

        shs += hcs;        shv0 += hv0;      shv1 += hv1;      shv2 += hv2;
        sgs += fs * hcs;   sgv0 += fv * hv0; sgv1 += fv * hv1; sgv2 += fv * hv2;
    }

    // -------- reduce over 16 a-groups: shuffle within wave, LDS across waves
    float vals[8] = {shs, shv0, shv1, shv2, sgs, sgv0, sgv1, sgv2};
#pragma unroll
    for (int q = 0; q < 8; ++q) {
        vals[q] += __shfl_xor(vals[q], 16, 64);
        vals[q] += __shfl_xor(vals[q], 32, 64);
    }
    const int wave = tid >> 6;
    if ((tid & 63) < 16) {
#pragma unroll
        for (int q = 0; q < 8; ++q) redW[wave][q][u] = vals[q];
    }
    __syncthreads();

    if (tid < 16) {
        float tacc[8];
#pragma unroll
        for (int q = 0; q < 8; ++q)
            tacc[q] = redW[0][q][tid] + redW[1][q][tid] + redW[2][q][tid] + redW[3][q][tid];
        sumHs[tid] = tacc[0];
        sumGs[tid] = tacc[4];
#pragma unroll
        for (int j = 0; j < 3; ++j) {
            sumHs[16 + tid * 3 + j] = tacc[1 + j];
            sumGs[16 + tid * 3 + j] = tacc[5 + j];
        }
    }
    __syncthreads();

    // -------- epilogue dots: 128 threads, one 32-MAC dot each --------
    // q: 0 zs | 1-3 zv[j] | 4 ps | 5-7 pv[j]; identical mm-order per dot.
    if (tid < 128) {
        const int q  = tid >> 4;       // 0..7
        const int uu = tid & 15;
        const float* xb   = x + (size_t)n * CHq * Nq + bnode;
        const float* Wrow = wsh[(q == 0) ? 0 : (q < 4) ? 1 : (q == 4) ? 2 : 3] + uu * 32;
        const float* SS   = (q < 4) ? sumHs : sumGs;
        const bool scalar = (q == 0) || (q == 4);
        const int  j      = scalar ? 0 : ((q < 4) ? (q - 1) : (q - 5));

        float acc = 0.f;
#pragma unroll
        for (int mm = 0; mm < 32; ++mm) {
            float val;
            if (scalar) val = (mm < 16) ? xb[mm * Nq] : SS[mm - 16];
            else        val = (mm < 16) ? xb[(16 + mm * 3 + j) * Nq]
                                        : SS[16 + (mm - 16) * 3 + j];
            acc += Wrow[mm] * val;
        }
        epish[q][uu] = acc;
    }
    __syncthreads();

    // -------- transcendental tail + output (16 threads) --------
    if (tid < 16) {
        const float zs_in = epish[0][tid];
        const float zv0i = epish[1][tid], zv1i = epish[2][tid], zv2i = epish[3][tid];
        const float ps_in = epish[4][tid];
        const float pv0i = epish[5][tid], pv1i = epish[6][tid], pv2i = epish[7][tid];

        const float zs  = 1.0f / (1.0f + __expf(-zs_in));
        const float zn  = sqrtf(zv0i * zv0i + zv1i * zv1i + zv2i * zv2i + EPSq);
        const float zsc = (1.0f / (1.0f + __expf(-zn))) / zn;
        const float zv0 = zv0i * zsc, zv1 = zv1i * zsc, zv2 = zv2i * zsc;
        const float phs = tanhf(ps_in);
        const float pn  = sqrtf(pv0i * pv0i + pv1i * pv1i + pv2i * pv2i + EPSq);
        const float psc = tanhf(pn) / pn;
        const float pv0 = pv0i * psc, pv1 = pv1i * psc, pv2 = pv2i * psc;
        const float gfs = fabsf(zs);
        const float gfv = sqrtf(zv0 * zv0 + zv1 * zv1 + zv2 * zv2 + EPSq);

        float* ob = out + (size_t)n * CHq * Nq + bnode;
        const float sh_s = sumHs[tid];
        ob[tid * Nq] = sh_s + gfs * (phs + sh_s);
#pragma unroll
        for (int j = 0; j < 3; ++j) {
            const float shv = sumHs[16 + tid * 3 + j];
            const float pvj = (j == 0) ? pv0 : ((j == 1) ? pv1 : pv2);
            ob[(16 + tid * 3 + j) * Nq] = shv + gfv * (pvj + shv);
        }
    }
}

// ---------------------------------------------------------------------------
extern "C" void kernel_launch(void* const* d_in, const int* in_sizes, int n_in,
                              void* d_out, int out_size, void* d_ws, size_t ws_size,
                              hipStream_t stream) {
    const float* x      = (const float*)d_in[0];
    const float* h_nei  = (const float*)d_in[1];
    const float* hdiff  = (const float*)d_in[2];
    const float* mask   = (const float*)d_in[3];
    const float* w00    = (const float*)d_in[4];
    const float* w10    = (const float*)d_in[5];
    const float* w01    = (const float*)d_in[6];
    const float* w11    = (const float*)d_in[7];
    const float* wz0    = (const float*)d_in[8];
    const float* wz1    = (const float*)d_in[9];
    const float* wr10   = (const float*)d_in[10];
    const float* wr11   = (const float*)d_in[11];
    const float* wr20   = (const float*)d_in[12];
    const float* wr21   = (const float*)d_in[13];
    const float* wp0    = (const float*)d_in[14];
    const float* wp1    = (const float*)d_in[15];
    float* out = (float*)d_out;
    float* pc  = (float*)d_ws;   // 320 * 24 * 16 * 16 B = 1,966,080 bytes

    se3_precomp<<<Bq * Nq, 256, 0, stream>>>(
        h_nei, x, w00, w10, w01, w11, wr10, wr11, wr20, wr21, pc);
    se3_main<<<Bq * Nq, 256, 0, stream>>>(
        x, hdiff, mask, wz0, wz1, wp0, wp1, pc, out);
}

// Round 13
// 23.969 us; speedup vs baseline: 1.1589x; 1.1589x over previous
//
#include <hip/hip_runtime.h>
#include <math.h>

// Problem constants (match reference)
#define Bq 4
#define Nq 80
#define CHq 64
#define GAMMAq 4.0f
#define EPSq 1e-6f
#define PCWL 100     // LDS row pad
#define NQUAD 24     // float4 quads per (na,u): 96 floats

// Packed comp map (per (na,u), 96 floats, stored as quads interleaved by u):
//   0-2   A00[k]        3-5   A10[k]       6-14  C01[k][j]
//   15-23 P0[k][j]      24-32 P1[k][j]     33-41 P2[k][j]
//   42 r1s  43-45 r1v   46-47 pad
//   48+c (c=0..41): wr2-mixed copies of comps 0..41 (r2 fold)   90-95 pad
// Global layout: pc_quad[ na ][ c4 0..23 ][ u 0..15 ]  (float4 each)
//
// XCD swizzle (both kernels, bijective over 320 tasks):
//   L = blockIdx & 7 (XCD lane), idx = blockIdx >> 3 (0..39)
//   n = L >> 1, node = (L & 1)*40 + idx
// -> pc[n][a-half] is produced AND consumed on the same XCD (L2-local).

// ---------------------------------------------------------------------------
// Kernel 1: 320 blocks x 192 threads, one (n,a) per block.
//  stage 0: cooperative LDS staging of all weights (coalesced; padded rows)
//  stage 1 (128 thr = 16u x {3k + r1} x 2 v-halves): 8-v contractions from LDS
//  stage 2 (96 thr): half-combine -> pout[u][0..45], zero pads
//  stage 3 (96 thr): r2 fold -> pout[u][48..89]
//  stage 4 (192 thr x 2): interleaved quad write-out
// ---------------------------------------------------------------------------
__global__ __launch_bounds__(192) void se3_precomp(
    const float* __restrict__ h_nei,   // [B][CH][N]
    const float* __restrict__ x,       // [B][CH][N]
    const float* __restrict__ w00,     // [M][M][3]
    const float* __restrict__ w10,
    const float* __restrict__ w01,
    const float* __restrict__ w11,     // [3][M][M][3]
    const float* __restrict__ wr10,    // [M][M]
    const float* __restrict__ wr11,
    const float* __restrict__ wr20,    // [M][M]
    const float* __restrict__ wr21,
    float* __restrict__ pc)
{
    const int L   = blockIdx.x & 7;
    const int idx = blockIdx.x >> 3;           // 0..39
    const int n   = L >> 1;
    const int a   = (L & 1) * 40 + idx;
    const int na  = n * Nq + a;
    const int tid = threadIdx.x;               // 0..191

    __shared__ float hsh[64];
    __shared__ float xsh[64];
    __shared__ float w00s[784], w10s[784], w01s[784];   // [u][v*3+k], 48->49 pad
    __shared__ float w11s[3][784];
    __shared__ float wr10s[272], wr11s[272];            // [u][v], 16->17 pad
    __shared__ float psh[2][42][16];
    __shared__ float r1sh[2][4][16];
    __shared__ float pout[16][PCWL];

    if (tid < 64)       hsh[tid]      = h_nei[(size_t)n * CHq * Nq + tid * Nq + a];
    else if (tid < 128) xsh[tid - 64] = x    [(size_t)n * CHq * Nq + (tid - 64) * Nq + a];

    // stage 0: weights -> LDS (coalesced global reads; padded LDS rows)
    for (int e = tid; e < 768; e += 192) {
        const int u = e / 48, r = e - u * 48;
        const int d = u * 49 + r;
        w00s[d]    = w00[e];
        w10s[d]    = w10[e];
        w01s[d]    = w01[e];
        w11s[0][d] = w11[e];
        w11s[1][d] = w11[768 + e];
        w11s[2][d] = w11[1536 + e];
    }
    for (int e = tid; e < 256; e += 192) {
        const int u = e >> 4, v = e & 15;
        wr10s[u * 17 + v] = wr10[e];
        wr11s[u * 17 + v] = wr11[e];
    }
    __syncthreads();

    // ---- stage 1: 128 threads = (u, q) with q = (kk 0..3, half) ----
    if (tid < 128) {
        const int u    = tid & 15;
        const int q    = tid >> 4;     // 0..7
        const int half = q & 1;
        const int kk   = q >> 1;       // 0..3
        const int v0   = half * 8;

        if (kk < 3) {
            const int k = kk;
            float a00 = 0.f, a10 = 0.f;
            float c[3] = {0.f,0.f,0.f}, p0[3] = {0.f,0.f,0.f};
            float p1[3] = {0.f,0.f,0.f}, p2[3] = {0.f,0.f,0.f};
#pragma unroll
            for (int i = 0; i < 8; ++i) {
                const int v  = v0 + i;
                const int wi = u * 49 + v * 3 + k;
                const float s = hsh[v];
                a00 += w00s[wi] * s;
                a10 += w10s[wi] * s;
                const float w01v = w01s[wi];
                const float w110 = w11s[0][wi];
                const float w111 = w11s[1][wi];
                const float w112 = w11s[2][wi];
#pragma unroll
                for (int j = 0; j < 3; ++j) {
                    const float Vj = hsh[16 + v * 3 + j];
                    c[j]  += w01v * Vj;
                    p0[j] += w110 * Vj;
                    p1[j] += w111 * Vj;
                    p2[j] += w112 * Vj;
                }
            }
            psh[half][0 + k][u] = a00;
            psh[half][3 + k][u] = a10;
#pragma unroll
            for (int j = 0; j < 3; ++j) {
                psh[half][6  + k * 3 + j][u] = c[j];
                psh[half][15 + k * 3 + j][u] = p0[j];
                psh[half][24 + k * 3 + j][u] = p1[j];
                psh[half][33 + k * 3 + j][u] = p2[j];
            }
        } else {
            // r1 = SI(x) partial for this v-half
            float r1s = 0.f, r1v[3] = {0.f, 0.f, 0.f};
#pragma unroll
            for (int i = 0; i < 8; ++i) {
                const int v = v0 + i;
                r1s += wr10s[u * 17 + v] * xsh[v];
                const float wv = wr11s[u * 17 + v];
#pragma unroll
                for (int j = 0; j < 3; ++j) r1v[j] += wv * xsh[16 + v * 3 + j];
            }
            r1sh[half][0][u] = r1s;
#pragma unroll
            for (int j = 0; j < 3; ++j) r1sh[half][1 + j][u] = r1v[j];
        }
    }
    __syncthreads();

    // ---- stage 2: half-combine (96 threads: u x kk 0..5, 7 comps each) ----
    if (tid < 96) {
        const int u  = tid & 15;
        const int kk = tid >> 4;       // 0..5
#pragma unroll
        for (int c = kk * 7; c < kk * 7 + 7; ++c)
            pout[u][c] = psh[0][c][u] + psh[1][c][u];
        if (kk == 0) {
#pragma unroll
            for (int j = 0; j < 4; ++j)
                pout[u][42 + j] = r1sh[0][j][u] + r1sh[1][j][u];
            pout[u][46] = 0.f; pout[u][47] = 0.f;
#pragma unroll
            for (int j = 90; j < 96; ++j) pout[u][j] = 0.f;
        }
    }
    __syncthreads();

    // ---- stage 3: r2 fold (96 threads; reads c<42, writes 48+c) ----
    if (tid < 96) {
        const int u  = tid & 15;
        const int kk = tid >> 4;
#pragma unroll
        for (int c = kk * 7; c < kk * 7 + 7; ++c) {
            const bool scalarType = (c < 3) || (c >= 6 && c < 15);
            const float* W = scalarType ? wr20 : wr21;
            float acc = 0.f;
#pragma unroll
            for (int v = 0; v < 16; ++v) acc += W[u * 16 + v] * pout[v][c];
            pout[u][48 + c] = acc;
        }
    }
    __syncthreads();

    // ---- stage 4: interleaved quad write (384 quad-tasks on 192 threads) ----
    {
        float4* dst = reinterpret_cast<float4*>(pc) + (size_t)na * (NQUAD * 16);
#pragma unroll
        for (int i = 0; i < 2; ++i) {
            const int qi = tid + i * 192;      // 0..383
            const int c4 = qi >> 4;
            const int u  = qi & 15;
            dst[c4 * 16 + u] = make_float4(pout[u][c4 * 4 + 0], pout[u][c4 * 4 + 1],
                                           pout[u][c4 * 4 + 2], pout[u][c4 * 4 + 3]);
        }
    }
}

// ---------------------------------------------------------------------------
// Kernel 2: 320 blocks x 256 threads (16 a-groups x 16 u), XCD-swizzled.
// Software-pipelined barrier-free a-loop: prefetch iteration i+1's pc row
// (registers, static [it&1] indices) while computing iteration i; all 5
// iterations' geometry hoisted upfront. launch_bounds(256,1): grid-limited,
// so the high VGPR count costs no occupancy.
// ---------------------------------------------------------------------------
__global__ __launch_bounds__(256, 1) void se3_main(
    const float* __restrict__ x,       // [B][CH][N]
    const float* __restrict__ hdiff,   // [B][N][N][3]
    const float* __restrict__ mask,    // [B][N][N]
    const float* __restrict__ wz0,     // [M][2M]
    const float* __restrict__ wz1,
    const float* __restrict__ wp0,
    const float* __restrict__ wp1,
    const float* __restrict__ pc,
    float* __restrict__ out)           // [B][CH][N]
{
    const int L     = blockIdx.x & 7;
    const int idx   = blockIdx.x >> 3;         // 0..39
    const int n     = L >> 1;
    const int bnode = (L & 1) * 40 + idx;
    const int tid   = threadIdx.x;
    const int g     = tid >> 4;        // a-group 0..15
    const int u     = tid & 15;        // channel 0..15

    __shared__ float wsh[4][512];      // wz0, wz1, wp0, wp1
    __shared__ float redW[4][8][16];
    __shared__ float sumHs[64], sumGs[64];

#pragma unroll
    for (int i = 0; i < 2; ++i) {
        const int widx = tid + i * 256;
        wsh[0][widx] = wz0[widx];
        wsh[1][widx] = wz1[widx];
        wsh[2][widx] = wp0[widx];
        wsh[3][widx] = wp1[widx];
    }

    const float* drow = hdiff + (size_t)(n * Nq + bnode) * Nq * 3;
    const float* mrow = mask  + (size_t)(n * Nq + bnode) * Nq;
    const float third = 1.0f / 3.0f;

    // hoist all geometry (static indices after unroll)
    float dg[5][3], mg[5];
#pragma unroll
    for (int it = 0; it < 5; ++it) {
        const int a = it * 16 + g;
        dg[it][0] = drow[a * 3 + 0];
        dg[it][1] = drow[a * 3 + 1];
        dg[it][2] = drow[a * 3 + 2];
        mg[it]    = mrow[a];
    }

    const float4* pcbase = reinterpret_cast<const float4*>(pc)
                         + (size_t)(n * Nq) * (NQUAD * 16) + u;

    float shs = 0.f, shv0 = 0.f, shv1 = 0.f, shv2 = 0.f;
    float sgs = 0.f, sgv0 = 0.f, sgv1 = 0.f, sgv2 = 0.f;

    float pa[2][48], pb[2][44];   // [it&1] static after full unroll -> registers

    // prologue: prefetch iteration 0
    {
        const float4* p4 = pcbase + (size_t)g * (NQUAD * 16);
#pragma unroll
        for (int i = 0; i < 12; ++i)
            *reinterpret_cast<float4*>(&pa[0][i * 4]) = p4[i * 16];
#pragma unroll
        for (int i = 0; i < 11; ++i)
            *reinterpret_cast<float4*>(&pb[0][i * 4]) = p4[(12 + i) * 16];
    }

#pragma unroll
    for (int it = 0; it < 5; ++it) {
        const int cur = it & 1, nxt = cur ^ 1;

        if (it < 4) {   // issue next iteration's loads; latency hides under compute
            const int a2 = (it + 1) * 16 + g;
            const float4* p4 = pcbase + (size_t)a2 * (NQUAD * 16);
#pragma unroll
            for (int i = 0; i < 12; ++i)
                *reinterpret_cast<float4*>(&pa[nxt][i * 4]) = p4[i * 16];
#pragma unroll
            for (int i = 0; i < 11; ++i)
                *reinterpret_cast<float4*>(&pb[nxt][i * 4]) = p4[(12 + i) * 16];
        }

        const float d0 = dg[it][0], d1 = dg[it][1], d2 = dg[it][2];
        const float m  = mg[it];

        const float rad = sqrtf(d0 * d0 + d1 * d1 + d2 * d2 + EPSq);
        const float inv = 1.0f / rad;
        const float nh0 = d0 * inv, nh1 = d1 * inv, nh2 = d2 * inv;
        float rb[3];
        rb[0] = __expf(-GAMMAq * rad * rad);
        { float t1 = rad - 0.5f; rb[1] = __expf(-GAMMAq * t1 * t1); }
        { float t2 = rad - 1.0f; rb[2] = __expf(-GAMMAq * t2 * t2); }

        float as_ = 0.f, a10 = 0.f;
        float c01[3] = {0.f,0.f,0.f}, p0[3] = {0.f,0.f,0.f};
        float p1[3] = {0.f,0.f,0.f}, p2[3] = {0.f,0.f,0.f};
        float bs_ = 0.f, b10 = 0.f;
        float bc01[3] = {0.f,0.f,0.f}, bp0[3] = {0.f,0.f,0.f};
        float bp1[3] = {0.f,0.f,0.f}, bp2[3] = {0.f,0.f,0.f};
#pragma unroll
        for (int k = 0; k < 3; ++k) {
            const float r = rb[k];
            as_ += r * pa[cur][0 + k];
            a10 += r * pa[cur][3 + k];
            bs_ += r * pb[cur][0 + k];
            b10 += r * pb[cur][3 + k];
#pragma unroll
            for (int j = 0; j < 3; ++j) {
                c01[j]  += r * pa[cur][6  + k * 3 + j];
                p0[j]   += r * pa[cur][15 + k * 3 + j];
                p1[j]   += r * pa[cur][24 + k * 3 + j];
                p2[j]   += r * pa[cur][33 + k * 3 + j];
                bc01[j] += r * pb[cur][6  + k * 3 + j];
                bp0[j]  += r * pb[cur][15 + k * 3 + j];
                bp1[j]  += r * pb[cur][24 + k * 3 + j];
                bp2[j]  += r * pb[cur][33 + k * 3 + j];
            }
        }

        const float hcs = m * (as_ + c01[0] * nh0 + c01[1] * nh1 + c01[2] * nh2);
        const float cr0 = p1[1] * nh2 - p1[2] * nh1;
        const float cr1 = p1[2] * nh0 - p1[0] * nh2;
        const float cr2 = p1[0] * nh1 - p1[1] * nh0;
        const float pd  = p2[0] * nh0 + p2[1] * nh1 + p2[2] * nh2;
        const float hv0 = m * (nh0 * a10 + p0[0] + cr0 + nh0 * pd - p2[0] * third);
        const float hv1 = m * (nh1 * a10 + p0[1] + cr1 + nh1 * pd - p2[1] * third);
        const float hv2 = m * (nh2 * a10 + p0[2] + cr2 + nh2 * pd - p2[2] * third);

        const float r2s = m * (bs_ + bc01[0] * nh0 + bc01[1] * nh1 + bc01[2] * nh2);
        const float br0 = bp1[1] * nh2 - bp1[2] * nh1;
        const float br1 = bp1[2] * nh0 - bp1[0] * nh2;
        const float br2 = bp1[0] * nh1 - bp1[1] * nh0;
        const float bpd = bp2[0] * nh0 + bp2[1] * nh1 + bp2[2] * nh2;
        const float r2v0 = m * (nh0 * b10 + bp0[0] + br0 + nh0 * bpd - bp2[0] * third);
        const float r2v1 = m * (nh1 * b10 + bp0[1] + br1 + nh1 * bpd - bp2[1] * third);
        const float r2v2 = m * (nh2 * b10 + bp0[2] + br2 + nh2 * bpd - bp2[2] * third);

        const float r1s  = pa[cur][42];
        const float r1v0 = pa[cur][43], r1v1 = pa[cur][44], r1v2 = pa[cur][45];

        const float rs  = 1.0f / (1.0f + __expf(-(r1s + r2s)));
        const float wv0 = r1v0 + r2v0, wv1 = r1v1 + r2v1, wv2 = r1v2 + r2v2;
        const float nn  = sqrtf(wv0 * wv0 + wv1 * wv1 + wv2 * wv2 + EPSq);
        const float sc  = (1.0f / (1.0f + __expf(-nn))) / nn;
        const float rv0 = wv0 * sc, rv1 = wv1 * sc, rv2 = wv2 * sc;
        const float fs  = fabsf(rs);
        const float fv  = sqrtf(rv0 * rv0 + rv1 * rv1 + rv2 * rv2 + EPSq);

        shs += hcs;        shv0 += hv0;      shv1 += hv1;      shv2 += hv2;
        sgs += fs * hcs;   sgv0 += fv * hv0; sgv1 += fv * hv1; sgv2 += fv * hv2;
    }

    // -------- reduce over 16 a-groups: shuffle within wave, LDS across waves
    float vals[8] = {shs, shv0, shv1, shv2, sgs, sgv0, sgv1, sgv2};
#pragma unroll
    for (int q = 0; q < 8; ++q) {
        vals[q] += __shfl_xor(vals[q], 16, 64);
        vals[q] += __shfl_xor(vals[q], 32, 64);
    }
    const int wave = tid >> 6;
    if ((tid & 63) < 16) {
#pragma unroll
        for (int q = 0; q < 8; ++q) redW[wave][q][u] = vals[q];
    }
    __syncthreads();

    if (tid < 16) {
        float tacc[8];
#pragma unroll
        for (int q = 0; q < 8; ++q)
            tacc[q] = redW[0][q][tid] + redW[1][q][tid] + redW[2][q][tid] + redW[3][q][tid];
        sumHs[tid] = tacc[0];
        sumGs[tid] = tacc[4];
#pragma unroll
        for (int j = 0; j < 3; ++j) {
            sumHs[16 + tid * 3 + j] = tacc[1 + j];
            sumGs[16 + tid * 3 + j] = tacc[5 + j];
        }
    }
    __syncthreads();

    // -------- epilogue: z, pre_h, new_h (16 threads; verified) --------
    if (tid < 16) {
        const float* xb = x + (size_t)n * CHq * Nq + bnode;

        float zs_in = 0.f, ps_in = 0.f;
        float zv[3] = {0.f, 0.f, 0.f};
        float pv[3] = {0.f, 0.f, 0.f};
#pragma unroll
        for (int mm = 0; mm < 32; ++mm) {
            float Sh, Sg;
            if (mm < 16) { const float xv = xb[mm * Nq]; Sh = xv; Sg = xv; }
            else         { Sh = sumHs[mm - 16]; Sg = sumGs[mm - 16]; }
            zs_in += wsh[0][tid * 32 + mm] * Sh;
            ps_in += wsh[2][tid * 32 + mm] * Sg;
            const float wz = wsh[1][tid * 32 + mm];
            const float wp = wsh[3][tid * 32 + mm];
#pragma unroll
            for (int j = 0; j < 3; ++j) {
                float Vh, Vg;
                if (mm < 16) { const float xv = xb[(16 + mm * 3 + j) * Nq]; Vh = xv; Vg = xv; }
                else { Vh = sumHs[16 + (mm - 16) * 3 + j]; Vg = sumGs[16 + (mm - 16) * 3 + j]; }
                zv[j] += wz * Vh;
                pv[j] += wp * Vg;
            }
        }

        const float zs  = 1.0f / (1.0f + __expf(-zs_in));
        const float zn  = sqrtf(zv[0] * zv[0] + zv[1] * zv[1] + zv[2] * zv[2] + EPSq);
        const float zsc = (1.0f / (1.0f + __expf(-zn))) / zn;
        const float zv0 = zv[0] * zsc, zv1 = zv[1] * zsc, zv2 = zv[2] * zsc;
        const float phs = tanhf(ps_in);
        const float pn  = sqrtf(pv[0] * pv[0] + pv[1] * pv[1] + pv[2] * pv[2] + EPSq);
        const float psc = tanhf(pn) / pn;
        const float pv0 = pv[0] * psc, pv1 = pv[1] * psc, pv2 = pv[2] * psc;
        const float gfs = fabsf(zs);
        const float gfv = sqrtf(zv0 * zv0 + zv1 * zv1 + zv2 * zv2 + EPSq);

        float* ob = out + (size_t)n * CHq * Nq + bnode;
        const float sh_s = sumHs[tid];
        ob[tid * Nq] = sh_s + gfs * (phs + sh_s);
#pragma unroll
        for (int j = 0; j < 3; ++j) {
            const float shv = sumHs[16 + tid * 3 + j];
            const float pvj = (j == 0) ? pv0 : ((j == 1) ? pv1 : pv2);
            ob[(16 + tid * 3 + j) * Nq] = shv + gfv * (pvj + shv);
        }
    }
}

// ---------------------------------------------------------------------------
extern "C" void kernel_launch(void* const* d_in, const int* in_sizes, int n_in,
                              void* d_out, int out_size, void* d_ws, size_t ws_size,
                              hipStream_t stream) {
    const float* x      = (const float*)d_in[0];
    const float* h_nei  = (const float*)d_in[1];
    const float* hdiff  = (const float*)d_in[2];
    const float* mask   = (const float*)d_in[3];
    const float* w00    = (const float*)d_in[4];
    const float* w10    = (const float*)d_in[5];
    const float* w01    = (const float*)d_in[6];
    const float* w11    = (const float*)d_in[7];
    const float* wz0    = (const float*)d_in[8];
    const float* wz1    = (const float*)d_in[9];
    const float* wr10   = (const float*)d_in[10];
    const float* wr11   = (const float*)d_in[11];
    const float* wr20   = (const float*)d_in[12];
    const float* wr21   = (const float*)d_in[13];
    const float* wp0    = (const float*)d_in[14];
    const float* wp1    = (const float*)d_in[15];
    float* out = (float*)d_out;
    float* pc  = (float*)d_ws;   // 320 * 24 * 16 * 16 B = 1,966,080 bytes

    se3_precomp<<<Bq * Nq, 192, 0, stream>>>(
        h_nei, x, w00, w10, w01, w11, wr10, wr11, wr20, wr21, pc);
    se3_main<<<Bq * Nq, 256, 0, stream>>>(
        x, hdiff, mask, wz0, wz1, wp0, wp1, pc, out);
}